// Round 17
// baseline (313.500 us; speedup 1.0000x reference)
//
#include <hip/hip_runtime.h>

#define C 128            // hidden/out channels
#define INCH 64          // input channels
#define FIXP 33554432.0f // 2^25 fixed-point scale for weighted degree

typedef unsigned short bf16_t;
typedef unsigned char fp8_t; // OCP e4m3fn
typedef float f32x4 __attribute__((ext_vector_type(4)));
typedef float f32x2 __attribute__((ext_vector_type(2)));
typedef unsigned int u32x4 __attribute__((ext_vector_type(4)));

__device__ __forceinline__ float silu_f(float v) {
    return v / (1.0f + __expf(-v));
}

// ---- bf16 helpers ----
__device__ __forceinline__ bf16_t f2bf(float f) {
    unsigned b = __float_as_uint(f);
    return (bf16_t)((b + 0x7FFFu + ((b >> 16) & 1u)) >> 16);
}
__device__ __forceinline__ float bf2f(unsigned u) {
    return __uint_as_float(u << 16);
}

// ---- fp8 e4m3fn helpers ----
__device__ __forceinline__ fp8_t f2fp8(float f) {
    unsigned b = __float_as_uint(f);
    unsigned s = (b >> 24) & 0x80u;
    unsigned a = b & 0x7FFFFFFFu;
    if (a >= 0x43E00000u) return (fp8_t)(s | 0x7E);   // |f| >= 448
    int e = (int)(a >> 23);
    int e8 = e - 120;                                  // e - 127 + 7
    if (e8 <= 0) {                                     // subnormal: units of 2^-9
        float av = __uint_as_float(a);
        int q = (int)(av * 512.0f + 0.5f);
        if (q > 8) q = 8;
        return (fp8_t)(s | (unsigned)q);
    }
    unsigned m = a & 0x7FFFFFu;
    unsigned m3 = m >> 20;
    unsigned rest = m & 0xFFFFFu;
    if (rest > 0x80000u || (rest == 0x80000u && (m3 & 1u))) m3++;
    unsigned enc = ((unsigned)e8 << 3) + m3;
    if (enc >= 0x7Fu) enc = 0x7Eu;
    return (fp8_t)(s | enc);
}
__device__ __forceinline__ float fp82f(unsigned v) {
    unsigned s = (v & 0x80u) << 24;
    unsigned e = (v >> 3) & 0xFu;
    unsigned m = v & 7u;
    if (e) return __uint_as_float(s | ((e + 120u) << 23) | (m << 20));
    float f = (float)m * 0.001953125f;
    return __uint_as_float(s | __float_as_uint(f));
}
__device__ __forceinline__ float4 dec4(unsigned v) {
#if __has_builtin(__builtin_amdgcn_cvt_pk_f32_fp8)
    f32x2 lo = __builtin_amdgcn_cvt_pk_f32_fp8((int)v, false);
    f32x2 hi = __builtin_amdgcn_cvt_pk_f32_fp8((int)v, true);
    return make_float4(lo[0], lo[1], hi[0], hi[1]);
#else
    return make_float4(fp82f(v & 0xFFu), fp82f((v >> 8) & 0xFFu),
                       fp82f((v >> 16) & 0xFFu), fp82f(v >> 24));
#endif
}

// D = A(16x32) * B(32x16) + D, bf16 inputs, f32 acc.
__device__ __forceinline__ void mfma16x16x32(f32x4& d, u32x4 a, u32x4 b) {
    asm("v_mfma_f32_16x16x32_bf16 %0, %1, %2, %0" : "+v"(d) : "v"(a), "v"(b));
}

// ---------- small helpers ----------

// load NV*4 fp8 channels, decode to NV float4 (NV = 1 -> u32 load, NV = 2 -> u64 load)
template<int NV>
__device__ __forceinline__ void ld_dec(const fp8_t* p, float4* o) {
    if constexpr (NV == 1) {
        o[0] = dec4(*(const unsigned*)p);
    } else {
        uint2 u = *(const uint2*)p;
        o[0] = dec4(u.x);
        o[1] = dec4(u.y);
    }
}

__device__ __forceinline__ float4 vfma(const float4 v, float n, float4 a) {
    a.x = fmaf(v.x, n, a.x); a.y = fmaf(v.y, n, a.y);
    a.z = fmaf(v.z, n, a.z); a.w = fmaf(v.w, n, a.w); return a;
}
__device__ __forceinline__ float4 vmul(const float4 v, float s) {
    return make_float4(v.x * s, v.y * s, v.z * s, v.w * s);
}
__device__ __forceinline__ float4 vadd(const float4 a, const float4 b) {
    return make_float4(a.x + b.x, a.y + b.y, a.z + b.z, a.w + b.w);
}

// ---------- W -> lane-ordered bf16 B-fragment element ----------

__device__ __forceinline__ void wfrag_one(const float* W, bf16_t* Wf, int id, int K) {
    int KS = K / 32;
    int j = id & 7;
    int lane = (id >> 3) & 63;
    int rest = id >> 9;
    int ks = rest % KS;
    int nt = rest / KS;
    int col = nt * 16 + (lane & 15);
    int k = ks * 32 + (lane >> 4) * 8 + j;
    Wf[id] = f2bf(W[k * 128 + col]);
}

// ---------- hist + fused wfrag (wfrag runs in hist's idle shadow) ----------
// hist: one u64 atomic per edge: hi32 = count, lo32 = fixed-point sum of w.
// Returned old hi32 = this edge's within-row rank; packed with dst into one word
// (dst < 2^17, rank < 2^15: mean in-degree 16, Poisson tail << 32768).
// Blocks >= eb convert the three weight matrices to MFMA B-fragment order.

__global__ void hist_wfrag_k(const int* __restrict__ dst, const float* __restrict__ w,
                             unsigned long long* packed, unsigned* __restrict__ dstrank,
                             int E, int eb,
                             const float* __restrict__ W1, const float* __restrict__ W2,
                             const float* __restrict__ W3,
                             bf16_t* Wf1, bf16_t* Wf2, bf16_t* Wf3) {
    if ((int)blockIdx.x < eb) {
        int e = blockIdx.x * blockDim.x + threadIdx.x;
        if (e < E) {
            int d = dst[e];
            unsigned fx = (unsigned)(w[e] * FIXP + 0.5f);
            unsigned long long old =
                atomicAdd(&packed[d], (1ull << 32) | (unsigned long long)fx);
            dstrank[e] = ((unsigned)d << 15) | (unsigned)(old >> 32);
        }
    } else {
        int idx = (blockIdx.x - eb) * blockDim.x + threadIdx.x;
        const int n1 = INCH * C, n2 = C * C;
        if (idx < n1)                wfrag_one(W1, Wf1, idx, INCH);
        else if (idx < n1 + n2)      wfrag_one(W2, Wf2, idx - n1, C);
        else if (idx < n1 + 2 * n2)  wfrag_one(W3, Wf3, idx - n1 - n2, C);
    }
}

// ---------- x -> fp8 conversion, pre-scaled by dinv (X' = dinv * x) ----------
// INCH=64: 16 float4 per row -> row = i >> 4.

__global__ void cvt_fp8_k(const float* __restrict__ in, const float* __restrict__ dinv,
                          fp8_t* __restrict__ out, int n4) {
    int i = blockIdx.x * blockDim.x + threadIdx.x;
    if (i < n4) {
        float dv = dinv[i >> 4];
        float4 v = *(const float4*)&in[(size_t)i * 4];
        uchar4 u = make_uchar4(f2fp8(v.x * dv), f2fp8(v.y * dv),
                               f2fp8(v.z * dv), f2fp8(v.w * dv));
        *(uchar4*)&out[(size_t)i * 4] = u;
    }
}

// ---------- scan: packed(hi32=count) -> rowptr (exclusive), dinv inline ----------

#define SCAN_T 256
#define SCAN_E 1024

__global__ void scan1_k(const unsigned long long* __restrict__ packed,
                        int* rowptr, int* bsums, float* __restrict__ dinv, int N) {
    __shared__ int s[SCAN_T];
    int t = threadIdx.x;
    int base = blockIdx.x * SCAN_E + t * 4;
    int v[4];
    #pragma unroll
    for (int j = 0; j < 4; ++j) {
        int i = base + j;
        if (i < N) {
            unsigned long long p = packed[i];
            v[j] = (int)(p >> 32);
            float deg = 1.0f + (float)(unsigned)(p & 0xffffffffull) * (1.0f / FIXP);
            dinv[i] = rsqrtf(deg);          // deg >= 1 always
        } else v[j] = 0;
    }
    int sum = v[0] + v[1] + v[2] + v[3];
    s[t] = sum; __syncthreads();
    for (int off = 1; off < SCAN_T; off <<= 1) {
        int y = (t >= off) ? s[t - off] : 0;
        __syncthreads();
        s[t] += y;
        __syncthreads();
    }
    int incl = s[t];
    int excl = incl - sum;
    if (t == SCAN_T - 1) bsums[blockIdx.x] = incl;
    int run = excl;
    #pragma unroll
    for (int j = 0; j < 4; ++j) { int i = base + j; if (i < N) rowptr[i] = run; run += v[j]; }
}

// scan3 absorbs the bucket-offset prefix (<= ~98 bsums, L2-broadcast loop)

__global__ void scan3_k(int* rowptr, const int* __restrict__ bsums, int N, int E) {
    int i = blockIdx.x * blockDim.x + threadIdx.x;
    if (i < N) {
        int bucket = i >> 10;
        int off = 0;
        for (int b = 0; b < bucket; ++b) off += bsums[b];
        rowptr[i] += off;
    }
    if (i == 0) rowptr[N] = E;
}

// ---------- CSR fill: edata[pos] = (src << 15) | bf16(w) ----------
// 4 edges/thread: coalesced 16B loads, 4 independent rowptr gathers + stores in flight.

__global__ void fill_csr_k(const int* __restrict__ src, const float* __restrict__ w,
                           const int* __restrict__ rowptr, const unsigned* __restrict__ dstrank,
                           unsigned* edata, int E) {
    int e0 = (blockIdx.x * blockDim.x + threadIdx.x) * 4;
    if (e0 + 3 < E) {
        uint4  s4 = *(const uint4*)&src[e0];
        float4 w4 = *(const float4*)&w[e0];
        uint4  d4 = *(const uint4*)&dstrank[e0];
        int p0 = rowptr[d4.x >> 15] + (int)(d4.x & 0x7FFFu);
        int p1 = rowptr[d4.y >> 15] + (int)(d4.y & 0x7FFFu);
        int p2 = rowptr[d4.z >> 15] + (int)(d4.z & 0x7FFFu);
        int p3 = rowptr[d4.w >> 15] + (int)(d4.w & 0x7FFFu);
        edata[p0] = (s4.x << 15) | (unsigned)f2bf(w4.x);
        edata[p1] = (s4.y << 15) | (unsigned)f2bf(w4.y);
        edata[p2] = (s4.z << 15) | (unsigned)f2bf(w4.z);
        edata[p3] = (s4.w << 15) | (unsigned)f2bf(w4.w);
    } else {
        for (int e = e0; e < E; ++e) {
            unsigned dr = dstrank[e];
            int pos = rowptr[dr >> 15] + (int)(dr & 0x7FFFu);
            edata[pos] = ((unsigned)src[e] << 15) | (unsigned)f2bf(w[e]);
        }
    }
}

// ---------- aggregation (gather): A[d] = dinv[d] * ( X'[d] + sum_e w_e * X'[src_e] ) ----------
// X' = dinv*X stored fp8; f32 accumulation; bf16 output (feeds MFMA).
// 16-lane group per dst node (16 nodes/block); lane owns CH/16 channels (u64/u32 load).
// NO cross-lane ops, no barriers; 4-deep unrolled, clamp-and-zero predication.

template<int CH>
__launch_bounds__(256)
__global__ void agg_gather_k(const fp8_t* __restrict__ Xin, const unsigned* __restrict__ edata,
                             const int* __restrict__ rowptr, const float* __restrict__ dinv,
                             bf16_t* __restrict__ outbuf, int N) {
    constexpr int NCH = CH / 16;          // channels per lane: 8 or 4
    constexpr int NV  = NCH / 4;          // float4 chunks: 2 or 1
    const int g = threadIdx.x >> 4;       // group 0..15
    const int l = threadIdx.x & 15;       // lane in group
    const int d = blockIdx.x * 16 + g;
    if (d >= N) return;                   // safe: no barriers, no cross-lane below
    const int c = l * NCH;                // channel base

    float di = dinv[d];
    float4 a0[NV], a1[NV], a2[NV], a3[NV];
    ld_dec<NV>(&Xin[(size_t)d * CH + c], a0);        // self-loop: X'[d] (w=1)
    #pragma unroll
    for (int q = 0; q < NV; ++q) {
        a1[q] = make_float4(0.f, 0.f, 0.f, 0.f);
        a2[q] = a1[q]; a3[q] = a1[q];
    }
    const int beg = rowptr[d], end = rowptr[d + 1];
    for (int j = beg; j < end; j += 4) {
        int j1 = j + 1, j2 = j + 2, j3 = j + 3;
        unsigned m0 = edata[j];
        unsigned m1 = edata[j1 < end ? j1 : j];
        unsigned m2 = edata[j2 < end ? j2 : j];
        unsigned m3 = edata[j3 < end ? j3 : j];
        float n0 = bf2f(m0 & 0x7FFFu);
        float n1 = j1 < end ? bf2f(m1 & 0x7FFFu) : 0.f;
        float n2 = j2 < end ? bf2f(m2 & 0x7FFFu) : 0.f;
        float n3 = j3 < end ? bf2f(m3 & 0x7FFFu) : 0.f;
        float4 v0[NV], v1[NV], v2[NV], v3[NV];
        ld_dec<NV>(&Xin[(size_t)(m0 >> 15) * CH + c], v0);
        ld_dec<NV>(&Xin[(size_t)(m1 >> 15) * CH + c], v1);
        ld_dec<NV>(&Xin[(size_t)(m2 >> 15) * CH + c], v2);
        ld_dec<NV>(&Xin[(size_t)(m3 >> 15) * CH + c], v3);
        #pragma unroll
        for (int q = 0; q < NV; ++q) {
            a0[q] = vfma(v0[q], n0, a0[q]);
            a1[q] = vfma(v1[q], n1, a1[q]);
            a2[q] = vfma(v2[q], n2, a2[q]);
            a3[q] = vfma(v3[q], n3, a3[q]);
        }
    }
    #pragma unroll
    for (int q = 0; q < NV; ++q) {
        float4 acc = vmul(vadd(vadd(a0[q], a1[q]), vadd(a2[q], a3[q])), di);
        *(ushort4*)&outbuf[(size_t)d * CH + c + q * 4] =
            make_ushort4(f2bf(acc.x), f2bf(acc.y), f2bf(acc.z), f2bf(acc.w));
    }
}

// ---------- MFMA GEMM: y = silu(A @ W + bias), A bf16 [N][K], Wf pre-fragmented ----------
// 256 threads = 4 waves; block tile 64 rows x 128 cols; wave = 16 rows x 128 cols.
// A-frags straight from global; B-frags from Wf (coalesced, L2-resident). No LDS main path.
// D: col = lane&15, row = (lane>>4)*4 + j   [HW-verified mapping]
// POOL=false: write fp8 rows PRE-SCALED by dinv[r] (next gather source X').
// POOL=true : colsum of silu (unscaled) -> partial (f32).

template<int K, bool POOL>
__launch_bounds__(256)
__global__ void gemm_mfma_k(const bf16_t* __restrict__ A, const bf16_t* __restrict__ Wf,
                            const float* __restrict__ bias, const float* __restrict__ dinv,
                            void* __restrict__ outp, int N) {
    constexpr int KS = K / 32;
    const int tid = threadIdx.x;
    const int wid = tid >> 6;
    const int lane = tid & 63;
    const int r0 = blockIdx.x * 64 + wid * 16;
    const int col = lane & 15;
    const int kgrp = lane >> 4;

    int arow = r0 + col;
    if (arow > N - 1) arow = N - 1;     // clamp (results for r>=N discarded)

    f32x4 acc[8] = {};
    #pragma unroll
    for (int ks = 0; ks < KS; ++ks) {
        u32x4 a = *(const u32x4*)(A + (size_t)arow * K + ks * 32 + kgrp * 8);
        #pragma unroll
        for (int n = 0; n < 8; ++n) {
            u32x4 b = *(const u32x4*)(Wf + ((size_t)(n * KS + ks) * 64 + lane) * 8);
            mfma16x16x32(acc[n], a, b);
        }
    }

    const int rbase = r0 + kgrp * 4;
    if (!POOL) {
        fp8_t* out = (fp8_t*)outp;
        float dv[4];
        #pragma unroll
        for (int j = 0; j < 4; ++j) {
            int r = rbase + j;
            dv[j] = (r < N) ? dinv[r] : 0.f;
        }
        #pragma unroll
        for (int n = 0; n < 8; ++n) {
            float bc = bias[n * 16 + col];
            #pragma unroll
            for (int j = 0; j < 4; ++j) {
                int r = rbase + j;
                if (r < N)
                    out[(size_t)r * C + n * 16 + col] = f2fp8(silu_f(acc[n][j] + bc) * dv[j]);
            }
        }
    } else {
        float s[8];
        #pragma unroll
        for (int n = 0; n < 8; ++n) {
            float bc = bias[n * 16 + col];
            float t = 0.f;
            #pragma unroll
            for (int j = 0; j < 4; ++j) {
                int r = rbase + j;
                float v = silu_f(acc[n][j] + bc);
                t += (r < N) ? v : 0.f;
            }
            s[n] = t;
        }
        // wave-uniform cross-lane reduce over the 4 row-groups (all 64 lanes execute)
        #pragma unroll
        for (int n = 0; n < 8; ++n) {
            s[n] += __shfl_xor(s[n], 16);
            s[n] += __shfl_xor(s[n], 32);
        }
        __shared__ float part[4][C];
        if (lane < 16) {
            #pragma unroll
            for (int n = 0; n < 8; ++n) part[wid][n * 16 + lane] = s[n];
        }
        __syncthreads();
        if (tid < C) {
            float t = part[0][tid] + part[1][tid] + part[2][tid] + part[3][tid];
            ((float*)outp)[(size_t)blockIdx.x * C + tid] = t;
        }
    }
}

// ---------- 2-stage reduce of partials -> out ----------

__global__ void reduce1_k(const float* __restrict__ partial, float* __restrict__ p2,
                          int NB, int chunk) {
    int t = threadIdx.x;                      // 128 = channel
    int r0 = blockIdx.x * chunk;
    int r1 = r0 + chunk; if (r1 > NB) r1 = NB;
    float s = 0.f;
    for (int r = r0; r < r1; ++r) s += partial[(size_t)r * C + t];
    p2[(size_t)blockIdx.x * C + t] = s;
}

__global__ void reduce2_k(const float* __restrict__ p2, float* __restrict__ out,
                          int R1, float inv_n) {
    int t = threadIdx.x;                      // 128 = channel
    float s = 0.f;
    for (int r = 0; r < R1; ++r) s += p2[(size_t)r * C + t];
    out[t] = s * inv_n;
}

// ---------- launch ----------

extern "C" void kernel_launch(void* const* d_in, const int* in_sizes, int n_in,
                              void* d_out, int out_size, void* d_ws, size_t ws_size,
                              hipStream_t stream) {
    const float* x  = (const float*)d_in[0];
    const int*   ei = (const int*)d_in[1];
    const float* ew = (const float*)d_in[2];
    const float* W1 = (const float*)d_in[3];
    const float* b1 = (const float*)d_in[4];
    const float* W2 = (const float*)d_in[5];
    const float* b2 = (const float*)d_in[6];
    const float* W3 = (const float*)d_in[7];
    const float* b3 = (const float*)d_in[8];
    float* out = (float*)d_out;

    const int N = in_sizes[0] / INCH;
    const int E = in_sizes[1] / 2;
    const int* src = ei;
    const int* dst = ei + E;

    char* ws = (char*)d_ws;
    size_t off = 0;
    auto alloc = [&](size_t bytes) -> void* {
        void* p = ws + off;
        off += (bytes + 255) & ~(size_t)255;
        return p;
    };
    bf16_t*   A       = (bf16_t*)  alloc((size_t)N * C * sizeof(bf16_t));   // agg outputs (bf16)
    fp8_t*    Xh8     = (fp8_t*)   alloc((size_t)N * C);                    // X' activations (fp8)
    fp8_t*    x8      = (fp8_t*)   alloc((size_t)N * INCH);                 // x' fp8; reused as partial
    unsigned* edata   = (unsigned*)alloc((size_t)E * sizeof(unsigned));
    unsigned* dstrank = (unsigned*)alloc((size_t)E * sizeof(unsigned));
    int*      rowptr  = (int*)     alloc((size_t)(N + 1) * sizeof(int));
    unsigned long long* packed = (unsigned long long*)alloc((size_t)N * 8);
    float*    dinv    = (float*)   alloc((size_t)N * sizeof(float));
    int*      bsums   = (int*)     alloc(256 * sizeof(int));
    float*    p2      = (float*)   alloc(64 * C * sizeof(float));
    bf16_t*   Wf1     = (bf16_t*)  alloc((size_t)INCH * C * sizeof(bf16_t));
    bf16_t*   Wf2     = (bf16_t*)  alloc((size_t)C * C * sizeof(bf16_t));
    bf16_t*   Wf3     = (bf16_t*)  alloc((size_t)C * C * sizeof(bf16_t));
    (void)ws_size;

    const int nb = (N + 255) / 256;
    const int eb = (E + 255) / 256;
    const int sbk = (N + SCAN_E - 1) / SCAN_E;   // scan blocks (<=128)
    const int wtot = INCH * C + 2 * C * C;
    const int wb = (wtot + 255) / 256;           // wfrag tail blocks (160)

    // normalization + CSR build + conversions (wfrag fused into hist's idle shadow)
    hipMemsetAsync(packed, 0, (size_t)N * 8, stream);
    hist_wfrag_k<<<eb + wb, 256, 0, stream>>>(dst, ew, packed, dstrank, E, eb,
                                              W1, W2, W3, Wf1, Wf2, Wf3);
    scan1_k<<<sbk, SCAN_T, 0, stream>>>(packed, rowptr, bsums, dinv, N);
    scan3_k<<<nb, 256, 0, stream>>>(rowptr, bsums, N, E);
    fill_csr_k<<<(E / 4 + 255) / 256, 256, 0, stream>>>(src, ew, rowptr, dstrank, edata, E);
    const int cv4 = (N * INCH) / 4;
    cvt_fp8_k<<<(cv4 + 255) / 256, 256, 0, stream>>>(x, dinv, x8, cv4);

    const int ab  = (N + 15) / 16;             // agg blocks (16 nodes/block)
    const int gb2 = (N + 63) / 64;             // mfma-gemm blocks (64 rows/block)

    // commuted layers: y = silu(agg(x) @ W + b), agg via D^-1/2 (A+I) D^-1/2 factorization
    agg_gather_k<INCH><<<ab, 256, 0, stream>>>(x8, edata, rowptr, dinv, A, N);
    gemm_mfma_k<INCH, false><<<gb2, 256, 0, stream>>>(A, Wf1, b1, dinv, Xh8, N);
    agg_gather_k<C><<<ab, 256, 0, stream>>>(Xh8, edata, rowptr, dinv, A, N);
    gemm_mfma_k<C, false><<<gb2, 256, 0, stream>>>(A, Wf2, b2, dinv, Xh8, N);
    agg_gather_k<C><<<ab, 256, 0, stream>>>(Xh8, edata, rowptr, dinv, A, N);
    float* partial = (float*)x8;               // x8 free after layer-1 agg
    gemm_mfma_k<C, true><<<gb2, 256, 0, stream>>>(A, Wf3, b3, dinv, partial, N);

    // 2-stage mean reduce: partial[gb2][128] -> p2[64][128] -> out[128]
    const int R1 = 64;
    const int chunk = (gb2 + R1 - 1) / R1;
    reduce1_k<<<R1, 128, 0, stream>>>(partial, p2, gb2, chunk);
    reduce2_k<<<1, 128, 0, stream>>>(p2, out, R1, 1.0f / (float)N);
}